// Round 3
// baseline (475.712 us; speedup 1.0000x reference)
//
#include <hip/hip_runtime.h>
#include <math.h>

// Wave-synchronous phase boundary: scheduling barrier + compiler memory fence.
// Intra-wave LDS RAW is in-order on CDNA; this only stops compiler reordering.
#define WSYNC() do { __builtin_amdgcn_wave_barrier(); asm volatile("" ::: "memory"); } while (0)

constexpr int FS = 20;   // f32 matrix row stride (floats)
constexpr int AS = 34;   // f32 augmented row stride (floats), 32 active cols

struct alignas(16) WaveMem {
  union {
    float aug[16][AS];      // [Phi0 | I] augmented, f32 Gauss-Jordan (2176 B)
    float m3[16][FS];       // reused after inversion
  } u;
  float pinv[16][FS];       // Phi0_inv (f32, nan_to_num'd) — MUST be f32-LU-class
  float phi [16][FS];       // Phi
  float m1  [16][FS];       // X0_var -> init_var -> Hom_var
  float m2  [16][FS];       // rotating temp / Q / ext_s
  float vcoef[4][64];       // vcc, vsc, vcs, vss indexed p*8+q
  float lamr[8], lami[8], etr[8], eti[8];
  float vic[16], veu[16], vli[16], vhom[16];
};  // ~8704 B per wave; x4 = ~34.8 KB/block -> 4 blocks/CU

// C[i][j] = sum_k A[i][k] * (TRB ? B[j][k] : B[k][j]); lane=(i16, jg) does 4 cols.
template<bool TRB>
__device__ inline void mm16(float* C, const float* A, const float* Bm,
                            int i16, int jg, bool absdiag = false)
{
  const int j0 = jg * 4;
  float a0 = 0.f, a1 = 0.f, a2 = 0.f, a3 = 0.f;
#pragma unroll
  for (int k = 0; k < 16; ++k) {
    float av = A[i16 * FS + k];
    if (TRB) {
      a0 += av * Bm[(j0 + 0) * FS + k];
      a1 += av * Bm[(j0 + 1) * FS + k];
      a2 += av * Bm[(j0 + 2) * FS + k];
      a3 += av * Bm[(j0 + 3) * FS + k];
    } else {
      a0 += av * Bm[k * FS + j0 + 0];
      a1 += av * Bm[k * FS + j0 + 1];
      a2 += av * Bm[k * FS + j0 + 2];
      a3 += av * Bm[k * FS + j0 + 3];
    }
  }
  if (absdiag) {
    if (i16 == j0 + 0) a0 = fabsf(a0);
    if (i16 == j0 + 1) a1 = fabsf(a1);
    if (i16 == j0 + 2) a2 = fabsf(a2);
    if (i16 == j0 + 3) a3 = fabsf(a3);
  }
  C[i16 * FS + j0 + 0] = a0;
  C[i16 * FS + j0 + 1] = a1;
  C[i16 * FS + j0 + 2] = a2;
  C[i16 * FS + j0 + 3] = a3;
}

__device__ inline float n2n(float v) {
  if (isnan(v)) return 0.0f;
  if (isinf(v)) return v > 0.f ? 3.402823466e38f : -3.402823466e38f;
  return v;
}

__global__ __launch_bounds__(256) void nesde_kernel(
    const float* __restrict__ gX0, const float* __restrict__ gXv,
    const float* __restrict__ gU,  const float* __restrict__ gT,
    const float* __restrict__ gQ,  const float* __restrict__ gLr,
    const float* __restrict__ gLi, const float* __restrict__ gVr,
    const float* __restrict__ gVi, float* __restrict__ gOut0,
    float* __restrict__ gOut1, int B)
{
  __shared__ WaveMem sm[4];
  const int wid  = threadIdx.x >> 6;
  const int lane = threadIdx.x & 63;
  const int b = blockIdx.x * 4 + wid;
  if (b >= B) return;
  WaveMem& S = sm[wid];

  const int i16 = lane & 15;   // matrix row
  const int jg  = lane >> 4;   // col group (0..3)

  const float t = gT[b];

  // ---- lam + et = exp(lam*t) (lanes 0..7) ----
  if (lane < 8) {
    float lr = gLr[(size_t)b * 8 + lane];
    float li = gLi[(size_t)b * 8 + lane];
    S.lamr[lane] = lr; S.lami[lane] = li;
    float e = expf(lr * t);
    float sn, cs; sincosf(li * t, &sn, &cs);
    S.etr[lane] = e * cs;
    S.eti[lane] = e * sn;
  }
  WSYNC();

  // ---- build aug = [Phi0 | I] (f32) and phi = [Re(V*et) | Im(V*et)] ----
  {
    const float2 v2r = *(const float2*)(gVr + (size_t)b * 128 + lane * 2);
    const float2 v2i = *(const float2*)(gVi + (size_t)b * 128 + lane * 2);
    const int i = lane >> 2, j = (lane & 3) * 2;
    S.u.aug[i][j        ] = v2r.x;
    S.u.aug[i][j + 1    ] = v2r.y;
    S.u.aug[i][8 + j    ] = v2i.x;
    S.u.aug[i][8 + j + 1] = v2i.y;
    float er0 = S.etr[j],     ei0 = S.eti[j];
    float er1 = S.etr[j + 1], ei1 = S.eti[j + 1];
    S.phi[i][j        ] = v2r.x * er0 - v2i.x * ei0;
    S.phi[i][j + 1    ] = v2r.y * er1 - v2i.y * ei1;
    S.phi[i][8 + j    ] = v2r.x * ei0 + v2i.x * er0;
    S.phi[i][8 + j + 1] = v2r.y * ei1 + v2i.y * er1;
    const int jj0 = (lane & 3) * 4;
#pragma unroll
    for (int c = 0; c < 4; ++c)
      S.u.aug[i][16 + jj0 + c] = (i == jj0 + c) ? 1.0f : 0.0f;
  }
  WSYNC();

  // ---- Gauss-Jordan with partial pivoting, **f32** (must match the f32-LU
  //      garbage attractor of LAPACK/hipsolver at ill-conditioned batches) ----
  for (int k = 0; k < 16; ++k) {
    float pv = (i16 >= k) ? fabsf(S.u.aug[i16][k]) : -1.0f;
    int pidx = i16;
#pragma unroll
    for (int off = 8; off; off >>= 1) {
      float ov = __shfl_xor(pv, off);
      int   oi = __shfl_xor(pidx, off);
      if (ov > pv || (ov == pv && oi < pidx)) { pv = ov; pidx = oi; }
    }
    if (pidx != k && lane < 32) {
      float a  = S.u.aug[k][lane];
      float bb = S.u.aug[pidx][lane];
      S.u.aug[k][lane] = bb;
      S.u.aug[pidx][lane] = a;
    }
    WSYNC();
    float pivinv = 1.0f / S.u.aug[k][k];   // IEEE f32 divide (no fast-math)
    WSYNC();
    if (lane < 32) S.u.aug[k][lane] *= pivinv;
    WSYNC();
    float f[8];
#pragma unroll
    for (int uu = 0; uu < 8; ++uu) {
      int i = (lane + 64 * uu) >> 5;
      f[uu] = S.u.aug[i][k];
    }
    WSYNC();
#pragma unroll
    for (int uu = 0; uu < 8; ++uu) {
      int e = lane + 64 * uu, i = e >> 5, j = e & 31;
      if (i != k) S.u.aug[i][j] -= f[uu] * S.u.aug[k][j];
    }
    WSYNC();
  }

  // ---- extract Pinv (f32) with nan_to_num ----
  {
    float pv0[4];
#pragma unroll
    for (int uu = 0; uu < 4; ++uu) {
      int e = lane + 64 * uu, i = e >> 4, j = e & 15;
      pv0[uu] = n2n(S.u.aug[i][16 + j]);
    }
    WSYNC();
#pragma unroll
    for (int uu = 0; uu < 4; ++uu) {
      int e = lane + 64 * uu, i = e >> 4, j = e & 15;
      S.pinv[i][j] = pv0[uu];
    }
  }
  WSYNC();

  // ---- mean path: init_cond, ext_u, Hom, lambda_int, Part, out0 ----
  if (lane < 16)      S.vhom[lane]     = gX0[(size_t)b * 16 + lane];
  else if (lane < 32) S.veu[lane - 16] = gU [(size_t)b * 16 + (lane - 16)];
  WSYNC();
  {
    float d = 0.f;
    if (lane < 32) {
      const int i = lane & 15;
      const float* src = (lane < 16) ? S.vhom : S.veu;
#pragma unroll
      for (int k = 0; k < 16; ++k) d += S.pinv[i][k] * src[k];
    }
    WSYNC();
    if (lane < 16)      S.vic[lane] = d;
    else if (lane < 32) S.veu[lane - 16] = d;  // ext_u
  }
  WSYNC();
  if (lane < 16) {
    float h = 0.f;
#pragma unroll
    for (int k = 0; k < 16; ++k) h += S.phi[lane][k] * S.vic[k];
    S.vhom[lane] = h;  // Hom
  }
  if (lane < 8) {
    float la = -S.lamr[lane], th = S.lami[lane];
    float exps = expf(la * t);
    float sn, cs; sincosf(th * t, &sn, &cs);
    float denom = la * la + th * th;
    float sgn = (denom > 0.f) ? 1.f : ((denom < 0.f) ? -1.f : 0.f);
    float scale = sgn / fmaxf(denom, 1e-10f);
    float ci = scale * (exps * (la * cs + th * sn) - la);
    float si = scale * (exps * (la * sn - th * cs) + th);
    float e0 = S.veu[2 * lane], e1 = S.veu[2 * lane + 1];
    S.vli[2 * lane    ] = ci * e0 - si * e1;
    S.vli[2 * lane + 1] = si * e0 + ci * e1;
  }
  WSYNC();
  if (lane < 16) {
    float p = 0.f;
#pragma unroll
    for (int k = 0; k < 16; ++k) p += S.phi[lane][k] * S.vli[k];
    gOut0[(size_t)b * 16 + lane] = S.vhom[lane] + p;
  }
  WSYNC();

  // ---- load X0_var into m1 ----
  {
    const int i = lane >> 2, jj0 = (lane & 3) * 4;
    float4 xv4 = *(const float4*)(gXv + (size_t)b * 256 + lane * 4);
    *(float4*)&S.m1[i][jj0] = xv4;
  }
  WSYNC();
  // ---- init_var = Pinv @ X0_var @ Pinv^T ----
  mm16<false>(&S.m2[0][0], &S.pinv[0][0], &S.m1[0][0], i16, jg);
  WSYNC();
  mm16<true >(&S.m1[0][0], &S.m2[0][0], &S.pinv[0][0], i16, jg);
  WSYNC();
  // ---- Hom_var = Phi @ init_var @ Phi^T, |diag| ----
  mm16<false>(&S.m2[0][0], &S.phi[0][0], &S.m1[0][0], i16, jg);
  WSYNC();
  mm16<true >(&S.m1[0][0], &S.m2[0][0], &S.phi[0][0], i16, jg, true);
  WSYNC();
  // ---- load Q into m2 ----
  {
    const int i = lane >> 2, jj0 = (lane & 3) * 4;
    float4 q4 = *(const float4*)(gQ + (size_t)b * 256 + lane * 4);
    *(float4*)&S.m2[i][jj0] = q4;
  }
  WSYNC();
  // ---- ext_s = Pinv @ Q @ Pinv^T -> m2 ----
  mm16<false>(&S.u.m3[0][0], &S.pinv[0][0], &S.m2[0][0], i16, jg);
  WSYNC();
  mm16<true >(&S.m2[0][0], &S.u.m3[0][0], &S.pinv[0][0], i16, jg);
  WSYNC();
  // ---- vcoef: one (p,q) per lane ----
  {
    const int p = lane >> 3, q = lane & 7;
    float la  = -(S.lamr[p] + S.lamr[q]);
    float th1 = S.lami[p] + S.lami[q];
    float th2 = S.lami[q] - S.lami[p];
    float exps = expf(la * t);
    float s1, c1, s2, c2;
    sincosf(th1 * t, &s1, &c1);
    sincosf(th2 * t, &s2, &c2);
    float den1 = la * la + th1 * th1;
    float sg1 = (den1 > 0.f) ? 1.f : ((den1 < 0.f) ? -1.f : 0.f);
    float sc1 = sg1 / fmaxf(den1, 1e-10f);
    float cos1 = sc1 * (exps * (la * c1 + th1 * s1) - la);
    float sin1 = sc1 * (exps * (la * s1 - th1 * c1) + th1);
    float den2 = la * la + th2 * th2;
    float sg2 = (den2 > 0.f) ? 1.f : ((den2 < 0.f) ? -1.f : 0.f);
    float sc2 = sg2 / fmaxf(den2, 1e-10f);
    float cos2 = sc2 * (exps * (la * c2 + th2 * s2) - la);
    float sin2 = sc2 * (exps * (la * s2 - th2 * c2) + th2);
    S.vcoef[0][lane] = 0.5f * (cos1 + cos2);  // vcc
    S.vcoef[1][lane] = 0.5f * (sin1 + sin2);  // vsc
    S.vcoef[2][lane] = 0.5f * (sin1 - sin2);  // vcs
    S.vcoef[3][lane] = 0.5f * (cos2 - cos1);  // vss
  }
  WSYNC();
  // ---- sig_int: read ext_s (m2), write m3 ----
  {
    const int j0 = jg * 4;
    const int p = i16 >> 1, a = i16 & 1;
#pragma unroll
    for (int uu = 0; uu < 4; ++uu) {
      int j = j0 + uu, q = j >> 1, bb = j & 1;
      int pq = p * 8 + q;
      float vcc = S.vcoef[0][pq], vsc = S.vcoef[1][pq];
      float vcs = S.vcoef[2][pq], vss = S.vcoef[3][pq];
      float d11 = S.m2[2 * p][2 * q],     d12 = S.m2[2 * p][2 * q + 1];
      float d21 = S.m2[2 * p + 1][2 * q], d22 = S.m2[2 * p + 1][2 * q + 1];
      float r;
      if (a == 0)
        r = (bb == 0) ? (vcc * d11 - vsc * d21 - vcs * d12 + vss * d22)
                      : (vcs * d11 - vss * d21 + vcc * d12 - vsc * d22);
      else
        r = (bb == 0) ? (vsc * d11 + vcc * d21 - vss * d12 - vcs * d22)
                      : (vss * d11 + vcs * d21 + vsc * d12 + vcc * d22);
      S.u.m3[i16][j] = r;
    }
  }
  WSYNC();
  // ---- Part_var = Phi @ sig_int @ Phi^T; out1 = Hom_var + Part_var ----
  mm16<false>(&S.m2[0][0], &S.phi[0][0], &S.u.m3[0][0], i16, jg);
  WSYNC();
  {
    const int j0 = jg * 4;
    float a0 = 0.f, a1 = 0.f, a2 = 0.f, a3 = 0.f;
#pragma unroll
    for (int k = 0; k < 16; ++k) {
      float av = S.m2[i16][k];
      a0 += av * S.phi[j0 + 0][k];
      a1 += av * S.phi[j0 + 1][k];
      a2 += av * S.phi[j0 + 2][k];
      a3 += av * S.phi[j0 + 3][k];
    }
    float4 o;
    o.x = S.m1[i16][j0 + 0] + a0;
    o.y = S.m1[i16][j0 + 1] + a1;
    o.z = S.m1[i16][j0 + 2] + a2;
    o.w = S.m1[i16][j0 + 3] + a3;
    *(float4*)&gOut1[(size_t)b * 256 + i16 * 16 + j0] = o;
  }
}

extern "C" void kernel_launch(void* const* d_in, const int* in_sizes, int n_in,
                              void* d_out, int out_size, void* d_ws, size_t ws_size,
                              hipStream_t stream) {
  const float* X0 = (const float*)d_in[0];
  const float* Xv = (const float*)d_in[1];
  const float* U  = (const float*)d_in[2];
  const float* T  = (const float*)d_in[3];
  const float* Q  = (const float*)d_in[4];
  const float* Lr = (const float*)d_in[5];
  const float* Li = (const float*)d_in[6];
  const float* Vr = (const float*)d_in[7];
  const float* Vi = (const float*)d_in[8];
  const int B = in_sizes[3];
  float* out0 = (float*)d_out;
  float* out1 = (float*)d_out + (size_t)B * 16;
  const int blocks = (B + 3) / 4;
  hipLaunchKernelGGL(nesde_kernel, dim3(blocks), dim3(256), 0, stream,
                     X0, Xv, U, T, Q, Lr, Li, Vr, Vi, out0, out1, B);
}

// Round 4
// 366.616 us; speedup vs baseline: 1.2976x; 1.2976x over previous
//
#include <hip/hip_runtime.h>
#include <math.h>

// Wave-synchronous phase boundary: scheduling barrier + compiler memory fence.
// Intra-wave LDS ops complete in order on CDNA (validated round 3).
#define WSYNC() do { __builtin_amdgcn_wave_barrier(); asm volatile("" ::: "memory"); } while (0)

constexpr int FS = 20;   // padded stride (floats) for P/F/W: rows 16B-aligned, 2-way-max banks

struct alignas(16) WaveMem {
  float P[16 * FS];      // Phi0_inv
  float F[16 * FS];      // Phi
  float W[16 * FS];      // rotating work
  float L1[256];         // X0_var -> init_var -> Hom_var   (linear 16x16, B-chunk reads)
  float L4[256];         // Q -> ext_s -> Phi@sig_int       (linear 16x16)
  float4 vcoef[64];      // {vcc,vsc,vcs,vss} @ p*8+q
  float etr[8], eti[8], lamr[8], lami[8];
  float vx0[16], vu[16], vic[16];
};  // 7232 B/wave; x4 = 28928 B/block -> 5 blocks/CU

__device__ inline float n2n(float v) {
  if (isnan(v)) return 0.0f;
  if (isinf(v)) return v > 0.f ? 3.402823466e38f : -3.402823466e38f;
  return v;
}

// C[i16][j0..j0+3] = sum_k A[i16][k] * (TRB ? B[j][k] : B[k][j]); all b128 LDS ops.
template<bool TRB, int ASZ, int BSZ, int CSZ>
__device__ inline void mmv(float* C, const float* A, const float* Bm,
                           int i16, int jg, bool absdiag = false)
{
  const int j0 = jg << 2;
  float aA[16];
#pragma unroll
  for (int c = 0; c < 4; ++c) {
    float4 v = *(const float4*)&A[i16 * ASZ + 4 * c];
    aA[4*c+0] = v.x; aA[4*c+1] = v.y; aA[4*c+2] = v.z; aA[4*c+3] = v.w;
  }
  float acc[4];
  if (TRB) {
#pragma unroll
    for (int c = 0; c < 4; ++c) {
      float bB[16];
#pragma unroll
      for (int cc = 0; cc < 4; ++cc) {
        float4 v = *(const float4*)&Bm[(j0 + c) * BSZ + 4 * cc];
        bB[4*cc+0] = v.x; bB[4*cc+1] = v.y; bB[4*cc+2] = v.z; bB[4*cc+3] = v.w;
      }
      float s = 0.f;
#pragma unroll
      for (int k = 0; k < 16; ++k) s = fmaf(aA[k], bB[k], s);
      acc[c] = s;
    }
  } else {
    float a0 = 0.f, a1 = 0.f, a2 = 0.f, a3 = 0.f;
#pragma unroll
    for (int k = 0; k < 16; ++k) {
      float4 bv = *(const float4*)&Bm[k * BSZ + j0];
      a0 = fmaf(aA[k], bv.x, a0);
      a1 = fmaf(aA[k], bv.y, a1);
      a2 = fmaf(aA[k], bv.z, a2);
      a3 = fmaf(aA[k], bv.w, a3);
    }
    acc[0] = a0; acc[1] = a1; acc[2] = a2; acc[3] = a3;
  }
  if (absdiag) {
#pragma unroll
    for (int c = 0; c < 4; ++c) if (i16 == j0 + c) acc[c] = fabsf(acc[c]);
  }
  *(float4*)&C[i16 * CSZ + j0] = make_float4(acc[0], acc[1], acc[2], acc[3]);
}

__global__ __launch_bounds__(256, 5) void nesde_kernel(
    const float* __restrict__ gX0, const float* __restrict__ gXv,
    const float* __restrict__ gU,  const float* __restrict__ gT,
    const float* __restrict__ gQ,  const float* __restrict__ gLr,
    const float* __restrict__ gLi, const float* __restrict__ gVr,
    const float* __restrict__ gVi, float* __restrict__ gOut0,
    float* __restrict__ gOut1, int B)
{
  __shared__ WaveMem sm[4];
  const int wid  = threadIdx.x >> 6;
  const int lane = threadIdx.x & 63;
  const int b = blockIdx.x * 4 + wid;
  if (b >= B) return;
  WaveMem& S = sm[wid];

  const int r4  = lane >> 2;   // GJ row (0..15)
  const int q   = lane & 3;    // GJ quad (owns cols 8q..8q+7)
  const int i16 = lane & 15;   // matmul row
  const int jg  = lane >> 4;   // matmul col group

  const float t = gT[b];

  // ---- early global loads (latency hides under phase A/B/GJ) ----
  const float4 xv = *(const float4*)(gXv + (size_t)b * 256 + lane * 4);
  const float4 qv = *(const float4*)(gQ  + (size_t)b * 256 + lane * 4);
  float4 va = make_float4(0.f,0.f,0.f,0.f), vb = va;
  if (q < 2) {
    const float* src = (q == 0) ? gVr : gVi;
    va = *(const float4*)(src + (size_t)b * 128 + r4 * 8);
    vb = *(const float4*)(src + (size_t)b * 128 + r4 * 8 + 4);
  }
  float x0u = 0.f;
  if (q == 2) x0u = gX0[(size_t)b * 16 + r4];
  if (q == 3) x0u = gU [(size_t)b * 16 + r4];

  // ---- phase A: lam + et = exp(lam*t) (lanes 0..7) ----
  if (lane < 8) {
    float lr = gLr[(size_t)b * 8 + lane];
    float li = gLi[(size_t)b * 8 + lane];
    S.lamr[lane] = lr; S.lami[lane] = li;
    float e = expf(lr * t);
    float sn, cs; sincosf(li * t, &sn, &cs);
    S.etr[lane] = e * cs;
    S.eti[lane] = e * sn;
  }
  WSYNC();  // S0

  // ---- phase B: vcoef + phi + staging + aug-reg init ----
  {  // vcoef: one (p,q) per lane (identical math to round 3)
    const int p = lane >> 3, qq = lane & 7;
    float la  = -(S.lamr[p] + S.lamr[qq]);
    float th1 = S.lami[p] + S.lami[qq];
    float th2 = S.lami[qq] - S.lami[p];
    float exps = expf(la * t);
    float s1, c1, s2, c2;
    sincosf(th1 * t, &s1, &c1);
    sincosf(th2 * t, &s2, &c2);
    float den1 = la * la + th1 * th1;
    float sg1 = (den1 > 0.f) ? 1.f : ((den1 < 0.f) ? -1.f : 0.f);
    float sc1 = sg1 / fmaxf(den1, 1e-10f);
    float cos1 = sc1 * (exps * (la * c1 + th1 * s1) - la);
    float sin1 = sc1 * (exps * (la * s1 - th1 * c1) + th1);
    float den2 = la * la + th2 * th2;
    float sg2 = (den2 > 0.f) ? 1.f : ((den2 < 0.f) ? -1.f : 0.f);
    float sc2 = sg2 / fmaxf(den2, 1e-10f);
    float cos2 = sc2 * (exps * (la * c2 + th2 * s2) - la);
    float sin2 = sc2 * (exps * (la * s2 - th2 * c2) + th2);
    S.vcoef[lane] = make_float4(0.5f * (cos1 + cos2), 0.5f * (sin1 + sin2),
                                0.5f * (sin1 - sin2), 0.5f * (cos2 - cos1));
  }
  *(float4*)&S.L1[lane << 2] = xv;   // X0_var
  *(float4*)&S.L4[lane << 2] = qv;   // Q
  if (q == 2) S.vx0[r4] = x0u;
  if (q == 3) S.vu[r4]  = x0u;

  float myv[8] = { va.x, va.y, va.z, va.w, vb.x, vb.y, vb.z, vb.w };
  float ov[8];
#pragma unroll
  for (int e = 0; e < 8; ++e) ov[e] = __shfl_xor(myv[e], 1);  // q0<->q1: Vr<->Vi
  if (q < 2) {
    float4 er0 = *(const float4*)&S.etr[0], er1 = *(const float4*)&S.etr[4];
    float4 ei0 = *(const float4*)&S.eti[0], ei1 = *(const float4*)&S.eti[4];
    float er[8] = { er0.x, er0.y, er0.z, er0.w, er1.x, er1.y, er1.z, er1.w };
    float ei[8] = { ei0.x, ei0.y, ei0.z, ei0.w, ei1.x, ei1.y, ei1.z, ei1.w };
    float vr[8], vi[8], ph[8];
#pragma unroll
    for (int e = 0; e < 8; ++e) {
      vr[e] = (q == 0) ? myv[e] : ov[e];
      vi[e] = (q == 0) ? ov[e]  : myv[e];
    }
    if (q == 0) {
#pragma unroll
      for (int e = 0; e < 8; ++e) ph[e] = vr[e] * er[e] - vi[e] * ei[e];
      *(float4*)&S.F[r4 * FS + 0] = make_float4(ph[0], ph[1], ph[2], ph[3]);
      *(float4*)&S.F[r4 * FS + 4] = make_float4(ph[4], ph[5], ph[6], ph[7]);
    } else {
#pragma unroll
      for (int e = 0; e < 8; ++e) ph[e] = vr[e] * ei[e] + vi[e] * er[e];
      *(float4*)&S.F[r4 * FS + 8]  = make_float4(ph[0], ph[1], ph[2], ph[3]);
      *(float4*)&S.F[r4 * FS + 12] = make_float4(ph[4], ph[5], ph[6], ph[7]);
    }
  }

  // aug registers: lane (r4,q) owns aug[r4][8q..8q+7]; left=Phi0, right=I
  float a[8];
#pragma unroll
  for (int e = 0; e < 8; ++e) {
    float idv = 0.f;
    if (q == 2) idv = (r4 == e)     ? 1.f : 0.f;
    if (q == 3) idv = (r4 == 8 + e) ? 1.f : 0.f;
    a[e] = (q < 2) ? myv[e] : idv;
  }

  // ---- Gauss-Jordan, f32, partial pivoting, VIRTUAL swap (bit-identical
  //      arithmetic to the physical-swap version: same pivots, same FMAs) ----
  unsigned used = 0;
  int myk = 0;
#pragma unroll
  for (int k = 0; k < 16; ++k) {
    const int qk = k >> 3, ek = k & 7;
    float ck = __shfl(a[ek], (lane & 60) | qk);          // my row's col-k value
    float cand = ((used >> r4) & 1u) ? -1.0f : fabsf(ck);
    int idx = r4;
#pragma unroll
    for (int off = 4; off <= 32; off <<= 1) {
      float oc = __shfl_xor(cand, off);
      int   oi = __shfl_xor(idx,  off);
      if (oc > cand || (oc == cand && oi < idx)) { cand = oc; idx = oi; }
    }
    const int p = idx;
    float pval = __shfl(a[ek], (p << 2) | qk);
    float pivinv = 1.0f / pval;                           // IEEE f32 divide
    const bool isp = (r4 == p);
#pragma unroll
    for (int e = 0; e < 8; ++e) a[e] = isp ? a[e] * pivinv : a[e];
#pragma unroll
    for (int e = 0; e < 8; ++e) {
      float bp = __shfl(a[e], (p << 2) | q);              // scaled pivot row
      float upd = fmaf(-ck, bp, a[e]);
      a[e] = isp ? a[e] : upd;
    }
    used |= 1u << p;
    if (isp) myk = k;
  }

  // ---- extract Pinv: lane (r4, q>=2) holds inv[myk][8(q-2)..+7] ----
  if (q >= 2) {
    const int base = myk * FS + ((q - 2) << 3);
    *(float4*)&S.P[base]     = make_float4(n2n(a[0]), n2n(a[1]), n2n(a[2]), n2n(a[3]));
    *(float4*)&S.P[base + 4] = make_float4(n2n(a[4]), n2n(a[5]), n2n(a[6]), n2n(a[7]));
  }
  WSYNC();  // S1 — covers P, F, L1, L4, vx0, vu, vcoef

  // ---- mean path ----
  if (lane < 32) {   // D1: init_cond (lanes 0-15) and ext_u (16-31)
    const float* src = (lane < 16) ? S.vx0 : S.vu;
    float sv[16], pA[16];
#pragma unroll
    for (int c = 0; c < 4; ++c) {
      float4 v = *(const float4*)&src[4 * c];
      sv[4*c+0]=v.x; sv[4*c+1]=v.y; sv[4*c+2]=v.z; sv[4*c+3]=v.w;
      float4 pvv = *(const float4*)&S.P[i16 * FS + 4 * c];
      pA[4*c+0]=pvv.x; pA[4*c+1]=pvv.y; pA[4*c+2]=pvv.z; pA[4*c+3]=pvv.w;
    }
    float d = 0.f;
#pragma unroll
    for (int k = 0; k < 16; ++k) d = fmaf(pA[k], sv[k], d);
    if (lane < 16) S.vic[i16] = d; else S.vu[i16] = d;
  }
  WSYNC();  // S2
  if (lane < 8) {    // D2: lambda_int folded into vic
    float la = -S.lamr[lane], th = S.lami[lane];
    float exps = expf(la * t);
    float sn, cs; sincosf(th * t, &sn, &cs);
    float denom = la * la + th * th;
    float sgn = (denom > 0.f) ? 1.f : ((denom < 0.f) ? -1.f : 0.f);
    float scale = sgn / fmaxf(denom, 1e-10f);
    float ci = scale * (exps * (la * cs + th * sn) - la);
    float si = scale * (exps * (la * sn - th * cs) + th);
    float e0 = S.vu[2 * lane], e1 = S.vu[2 * lane + 1];
    S.vic[2 * lane]     += ci * e0 - si * e1;
    S.vic[2 * lane + 1] += si * e0 + ci * e1;
  }
  WSYNC();  // S3
  if (lane < 16) {   // D3: out0 = Phi @ (init_cond + lambda_int)
    float fA[16], vv[16];
#pragma unroll
    for (int c = 0; c < 4; ++c) {
      float4 fv = *(const float4*)&S.F[lane * FS + 4 * c];
      fA[4*c+0]=fv.x; fA[4*c+1]=fv.y; fA[4*c+2]=fv.z; fA[4*c+3]=fv.w;
      float4 cv = *(const float4*)&S.vic[4 * c];
      vv[4*c+0]=cv.x; vv[4*c+1]=cv.y; vv[4*c+2]=cv.z; vv[4*c+3]=cv.w;
    }
    float d = 0.f;
#pragma unroll
    for (int k = 0; k < 16; ++k) d = fmaf(fA[k], vv[k], d);
    gOut0[(size_t)b * 16 + lane] = d;
  }
  WSYNC();  // S3b (out0 reads done before L1 overwritten below? L1 untouched; keep for vic WAR safety)

  // ---- variance path ----
  mmv<false, FS, 16, FS>(S.W,  S.P, S.L1, i16, jg);        WSYNC();  // W = Pinv @ X0_var
  mmv<true,  FS, FS, 16>(S.L1, S.W, S.P,  i16, jg);        WSYNC();  // L1 = init_var
  mmv<false, FS, 16, FS>(S.W,  S.F, S.L1, i16, jg);        WSYNC();  // W = Phi @ init_var
  mmv<true,  FS, FS, 16>(S.L1, S.W, S.F,  i16, jg, true);  WSYNC();  // L1 = Hom_var (|diag|)
  mmv<false, FS, 16, FS>(S.W,  S.P, S.L4, i16, jg);        WSYNC();  // W = Pinv @ Q
  mmv<true,  FS, FS, 16>(S.L4, S.W, S.P,  i16, jg);        WSYNC();  // L4 = ext_s

  {  // sig_int -> W
    const int j0 = jg << 2;
    const int p2 = i16 >> 1, aa = i16 & 1;
    float4 top = *(const float4*)&S.L4[(2 * p2) * 16 + j0];
    float4 bot = *(const float4*)&S.L4[(2 * p2 + 1) * 16 + j0];
    float tl[4] = { top.x, top.y, top.z, top.w };
    float bl[4] = { bot.x, bot.y, bot.z, bot.w };
    float4 c0 = S.vcoef[p2 * 8 + (j0 >> 1)];
    float4 c1 = S.vcoef[p2 * 8 + (j0 >> 1) + 1];
    float r[4];
#pragma unroll
    for (int uu = 0; uu < 4; ++uu) {
      float4 c = (uu < 2) ? c0 : c1;
      const int off = 2 * (uu >> 1);
      float d11 = tl[off], d12 = tl[off + 1];
      float d21 = bl[off], d22 = bl[off + 1];
      float vcc = c.x, vsc = c.y, vcs = c.z, vss = c.w;
      const int bb = uu & 1;
      if (aa == 0)
        r[uu] = (bb == 0) ? (vcc * d11 - vsc * d21 - vcs * d12 + vss * d22)
                          : (vcs * d11 - vss * d21 + vcc * d12 - vsc * d22);
      else
        r[uu] = (bb == 0) ? (vsc * d11 + vcc * d21 - vss * d12 - vcs * d22)
                          : (vss * d11 + vcs * d21 + vsc * d12 + vcc * d22);
    }
    *(float4*)&S.W[i16 * FS + j0] = make_float4(r[0], r[1], r[2], r[3]);
  }
  WSYNC();
  mmv<false, FS, FS, 16>(S.L4, S.F, S.W, i16, jg);         WSYNC();  // L4 = Phi @ sig_int

  {  // out1 = Hom_var + L4 @ Phi^T
    const int j0 = jg << 2;
    float aA[16];
#pragma unroll
    for (int c = 0; c < 4; ++c) {
      float4 v = *(const float4*)&S.L4[i16 * 16 + 4 * c];
      aA[4*c+0]=v.x; aA[4*c+1]=v.y; aA[4*c+2]=v.z; aA[4*c+3]=v.w;
    }
    float acc[4];
#pragma unroll
    for (int c = 0; c < 4; ++c) {
      float bB[16];
#pragma unroll
      for (int cc = 0; cc < 4; ++cc) {
        float4 v = *(const float4*)&S.F[(j0 + c) * FS + 4 * cc];
        bB[4*cc+0]=v.x; bB[4*cc+1]=v.y; bB[4*cc+2]=v.z; bB[4*cc+3]=v.w;
      }
      float s = 0.f;
#pragma unroll
      for (int k = 0; k < 16; ++k) s = fmaf(aA[k], bB[k], s);
      acc[c] = s;
    }
    float4 hv = *(const float4*)&S.L1[i16 * 16 + j0];
    float4 o = make_float4(hv.x + acc[0], hv.y + acc[1], hv.z + acc[2], hv.w + acc[3]);
    *(float4*)&gOut1[(size_t)b * 256 + i16 * 16 + j0] = o;
  }
}

extern "C" void kernel_launch(void* const* d_in, const int* in_sizes, int n_in,
                              void* d_out, int out_size, void* d_ws, size_t ws_size,
                              hipStream_t stream) {
  const float* X0 = (const float*)d_in[0];
  const float* Xv = (const float*)d_in[1];
  const float* U  = (const float*)d_in[2];
  const float* T  = (const float*)d_in[3];
  const float* Q  = (const float*)d_in[4];
  const float* Lr = (const float*)d_in[5];
  const float* Li = (const float*)d_in[6];
  const float* Vr = (const float*)d_in[7];
  const float* Vi = (const float*)d_in[8];
  const int B = in_sizes[3];
  float* out0 = (float*)d_out;
  float* out1 = (float*)d_out + (size_t)B * 16;
  const int blocks = (B + 3) / 4;
  hipLaunchKernelGGL(nesde_kernel, dim3(blocks), dim3(256), 0, stream,
                     X0, Xv, U, T, Q, Lr, Li, Vr, Vi, out0, out1, B);
}

// Round 5
// 315.483 us; speedup vs baseline: 1.5079x; 1.1621x over previous
//
#include <hip/hip_runtime.h>
#include <math.h>

// Wave-synchronous phase boundary: scheduling barrier + compiler memory fence.
// Intra-wave LDS ops complete in order on CDNA (validated rounds 3-4).
#define WSYNC() do { __builtin_amdgcn_wave_barrier(); asm volatile("" ::: "memory"); } while (0)

constexpr int FS = 20;   // padded stride (floats) for P/F/W: rows 16B-aligned

struct alignas(16) WaveMem {
  float P[16 * FS];      // Phi0_inv
  float F[16 * FS];      // Phi
  float W[16 * FS];      // rotating work
  float L1[256];         // X0_var -> init_var -> Hom_var   (linear 16x16)
  float L4[256];         // Q -> ext_s -> Phi@sig_int       (linear 16x16)
  float etr[8], eti[8], lamr[8], lami[8];
  float vx0[16], vu[16], vic[16];
};  // 6208 B/wave; x4 = 24832 B/block -> 6 blocks/CU

__device__ inline float n2n(float v) {
  if (isnan(v)) return 0.0f;
  if (isinf(v)) return v > 0.f ? 3.402823466e38f : -3.402823466e38f;
  return v;
}

__device__ inline float readlane_f(float v, int l) {
  return __int_as_float(__builtin_amdgcn_readlane(__float_as_int(v), l));
}

// C[i16][j0..j0+3] = sum_k A[i16][k] * (TRB ? B[j][k] : B[k][j]); all b128 LDS ops.
template<bool TRB, int ASZ, int BSZ, int CSZ>
__device__ inline void mmv(float* C, const float* A, const float* Bm,
                           int i16, int jg, bool absdiag = false)
{
  const int j0 = jg << 2;
  float aA[16];
#pragma unroll
  for (int c = 0; c < 4; ++c) {
    float4 v = *(const float4*)&A[i16 * ASZ + 4 * c];
    aA[4*c+0] = v.x; aA[4*c+1] = v.y; aA[4*c+2] = v.z; aA[4*c+3] = v.w;
  }
  float acc[4];
  if (TRB) {
#pragma unroll
    for (int c = 0; c < 4; ++c) {
      float bB[16];
#pragma unroll
      for (int cc = 0; cc < 4; ++cc) {
        float4 v = *(const float4*)&Bm[(j0 + c) * BSZ + 4 * cc];
        bB[4*cc+0] = v.x; bB[4*cc+1] = v.y; bB[4*cc+2] = v.z; bB[4*cc+3] = v.w;
      }
      float s = 0.f;
#pragma unroll
      for (int k = 0; k < 16; ++k) s = fmaf(aA[k], bB[k], s);
      acc[c] = s;
    }
  } else {
    float a0 = 0.f, a1 = 0.f, a2 = 0.f, a3 = 0.f;
#pragma unroll
    for (int k = 0; k < 16; ++k) {
      float4 bv = *(const float4*)&Bm[k * BSZ + j0];
      a0 = fmaf(aA[k], bv.x, a0);
      a1 = fmaf(aA[k], bv.y, a1);
      a2 = fmaf(aA[k], bv.z, a2);
      a3 = fmaf(aA[k], bv.w, a3);
    }
    acc[0] = a0; acc[1] = a1; acc[2] = a2; acc[3] = a3;
  }
  if (absdiag) {
#pragma unroll
    for (int c = 0; c < 4; ++c) if (i16 == j0 + c) acc[c] = fabsf(acc[c]);
  }
  *(float4*)&C[i16 * CSZ + j0] = make_float4(acc[0], acc[1], acc[2], acc[3]);
}

__global__ __launch_bounds__(256, 6) void nesde_kernel(
    const float* __restrict__ gX0, const float* __restrict__ gXv,
    const float* __restrict__ gU,  const float* __restrict__ gT,
    const float* __restrict__ gQ,  const float* __restrict__ gLr,
    const float* __restrict__ gLi, const float* __restrict__ gVr,
    const float* __restrict__ gVi, float* __restrict__ gOut0,
    float* __restrict__ gOut1, int B)
{
  __shared__ WaveMem sm[4];
  const int wid  = threadIdx.x >> 6;
  const int lane = threadIdx.x & 63;
  const int b = blockIdx.x * 4 + wid;
  if (b >= B) return;
  WaveMem& S = sm[wid];

  const int r4  = lane >> 2;   // GJ row (0..15)
  const int q   = lane & 3;    // GJ quad (owns cols 8q..8q+7)
  const int i16 = lane & 15;   // matmul row
  const int jg  = lane >> 4;   // matmul col group

  const float t = gT[b];

  // ---- early global loads (latency hides under phase A/B/GJ) ----
  const float4 xv = *(const float4*)(gXv + (size_t)b * 256 + lane * 4);
  const float4 qv = *(const float4*)(gQ  + (size_t)b * 256 + lane * 4);
  float4 va = make_float4(0.f,0.f,0.f,0.f), vb = va;
  if (q < 2) {
    const float* src = (q == 0) ? gVr : gVi;
    va = *(const float4*)(src + (size_t)b * 128 + r4 * 8);
    vb = *(const float4*)(src + (size_t)b * 128 + r4 * 8 + 4);
  }
  float x0u = 0.f;
  if (q == 2) x0u = gX0[(size_t)b * 16 + r4];
  if (q == 3) x0u = gU [(size_t)b * 16 + r4];

  // ---- phase A: lam + et = exp(lam*t) (lanes 0..7) ----
  if (lane < 8) {
    float lr = gLr[(size_t)b * 8 + lane];
    float li = gLi[(size_t)b * 8 + lane];
    S.lamr[lane] = lr; S.lami[lane] = li;
    float e = expf(lr * t);
    float sn, cs; sincosf(li * t, &sn, &cs);
    S.etr[lane] = e * cs;
    S.eti[lane] = e * sn;
  }
  WSYNC();  // S0

  // ---- phase B: vcoef (-> registers) + phi + staging + aug-reg init ----
  float4 vco;
  {  // vcoef: one (p,q) per lane (identical math to rounds 3-4)
    const int p = lane >> 3, qq = lane & 7;
    float la  = -(S.lamr[p] + S.lamr[qq]);
    float th1 = S.lami[p] + S.lami[qq];
    float th2 = S.lami[qq] - S.lami[p];
    float exps = expf(la * t);
    float s1, c1, s2, c2;
    sincosf(th1 * t, &s1, &c1);
    sincosf(th2 * t, &s2, &c2);
    float den1 = la * la + th1 * th1;
    float sg1 = (den1 > 0.f) ? 1.f : ((den1 < 0.f) ? -1.f : 0.f);
    float sc1 = sg1 / fmaxf(den1, 1e-10f);
    float cos1 = sc1 * (exps * (la * c1 + th1 * s1) - la);
    float sin1 = sc1 * (exps * (la * s1 - th1 * c1) + th1);
    float den2 = la * la + th2 * th2;
    float sg2 = (den2 > 0.f) ? 1.f : ((den2 < 0.f) ? -1.f : 0.f);
    float sc2 = sg2 / fmaxf(den2, 1e-10f);
    float cos2 = sc2 * (exps * (la * c2 + th2 * s2) - la);
    float sin2 = sc2 * (exps * (la * s2 - th2 * c2) + th2);
    vco = make_float4(0.5f * (cos1 + cos2), 0.5f * (sin1 + sin2),
                      0.5f * (sin1 - sin2), 0.5f * (cos2 - cos1));
  }
  *(float4*)&S.L1[lane << 2] = xv;   // X0_var
  *(float4*)&S.L4[lane << 2] = qv;   // Q
  if (q == 2) S.vx0[r4] = x0u;
  if (q == 3) S.vu[r4]  = x0u;

  float myv[8] = { va.x, va.y, va.z, va.w, vb.x, vb.y, vb.z, vb.w };
  float ov[8];
#pragma unroll
  for (int e = 0; e < 8; ++e) ov[e] = __shfl_xor(myv[e], 1);  // q0<->q1: Vr<->Vi
  if (q < 2) {
    float4 er0 = *(const float4*)&S.etr[0], er1 = *(const float4*)&S.etr[4];
    float4 ei0 = *(const float4*)&S.eti[0], ei1 = *(const float4*)&S.eti[4];
    float er[8] = { er0.x, er0.y, er0.z, er0.w, er1.x, er1.y, er1.z, er1.w };
    float ei[8] = { ei0.x, ei0.y, ei0.z, ei0.w, ei1.x, ei1.y, ei1.z, ei1.w };
    float vr[8], vi[8], ph[8];
#pragma unroll
    for (int e = 0; e < 8; ++e) {
      vr[e] = (q == 0) ? myv[e] : ov[e];
      vi[e] = (q == 0) ? ov[e]  : myv[e];
    }
    if (q == 0) {
#pragma unroll
      for (int e = 0; e < 8; ++e) ph[e] = vr[e] * er[e] - vi[e] * ei[e];
      *(float4*)&S.F[r4 * FS + 0] = make_float4(ph[0], ph[1], ph[2], ph[3]);
      *(float4*)&S.F[r4 * FS + 4] = make_float4(ph[4], ph[5], ph[6], ph[7]);
    } else {
#pragma unroll
      for (int e = 0; e < 8; ++e) ph[e] = vr[e] * ei[e] + vi[e] * er[e];
      *(float4*)&S.F[r4 * FS + 8]  = make_float4(ph[0], ph[1], ph[2], ph[3]);
      *(float4*)&S.F[r4 * FS + 12] = make_float4(ph[4], ph[5], ph[6], ph[7]);
    }
  }

  // aug registers: lane (r4,q) owns aug[r4][8q..8q+7]; left=Phi0, right=I
  float a[8];
#pragma unroll
  for (int e = 0; e < 8; ++e) {
    float idv = 0.f;
    if (q == 2) idv = (r4 == e)     ? 1.f : 0.f;
    if (q == 3) idv = (r4 == 8 + e) ? 1.f : 0.f;
    a[e] = (q < 2) ? myv[e] : idv;
  }

  // ---- Gauss-Jordan, f32, partial pivoting, virtual swap.
  //      Bit-identical arithmetic to rounds 3-4: same pivot choices
  //      (max |value|, lowest row on ties), same single-rounded products. ----
  unsigned used = 0;
  int myk = 0;
#pragma unroll
  for (int k = 0; k < 16; ++k) {
    const int qk = k >> 3, ek = k & 7;
    float ck = __shfl(a[ek], (lane & 60) | qk);      // my row's col-k value
    float cand = ((used >> r4) & 1u) ? -1.0f : fabsf(ck);
    float mx = cand;
#pragma unroll
    for (int off = 4; off <= 32; off <<= 1) mx = fmaxf(mx, __shfl_xor(mx, off));
    // exact argmax-with-min-index: first row attaining mx (scalar path)
    unsigned long long msk = __ballot(cand == mx);
    const int pl4 = (__ffsll(msk) - 1) & 60;         // 4*p (SGPR-uniform)
    const int p = pl4 >> 2;
    float pval = readlane_f(a[ek], pl4 | qk);        // uniform readlane
    float pivinv = 1.0f / pval;                      // IEEE f32 divide
    const bool isp = (r4 == p);
#pragma unroll
    for (int e = 0; e < 8; ++e) {
      float bpr = __shfl(a[e], pl4 | q);             // raw pivot row, my cols
      float sp  = bpr * pivinv;                      // == scaled pivot row
      a[e] = isp ? sp : fmaf(-ck, sp, a[e]);
    }
    used |= 1u << p;
    if (isp) myk = k;
  }

  // ---- extract Pinv: lane (r4, q>=2) holds inv[myk][8(q-2)..+7] ----
  if (q >= 2) {
    const int base = myk * FS + ((q - 2) << 3);
    *(float4*)&S.P[base]     = make_float4(n2n(a[0]), n2n(a[1]), n2n(a[2]), n2n(a[3]));
    *(float4*)&S.P[base + 4] = make_float4(n2n(a[4]), n2n(a[5]), n2n(a[6]), n2n(a[7]));
  }
  WSYNC();  // S1 — covers P, F, L1, L4, vx0, vu

  // ---- mean path ----
  if (lane < 32) {   // D1: init_cond (lanes 0-15) and ext_u (16-31)
    const float* src = (lane < 16) ? S.vx0 : S.vu;
    float sv[16], pA[16];
#pragma unroll
    for (int c = 0; c < 4; ++c) {
      float4 v = *(const float4*)&src[4 * c];
      sv[4*c+0]=v.x; sv[4*c+1]=v.y; sv[4*c+2]=v.z; sv[4*c+3]=v.w;
      float4 pvv = *(const float4*)&S.P[i16 * FS + 4 * c];
      pA[4*c+0]=pvv.x; pA[4*c+1]=pvv.y; pA[4*c+2]=pvv.z; pA[4*c+3]=pvv.w;
    }
    float d = 0.f;
#pragma unroll
    for (int k = 0; k < 16; ++k) d = fmaf(pA[k], sv[k], d);
    if (lane < 16) S.vic[i16] = d; else S.vu[i16] = d;
  }
  WSYNC();  // S2
  if (lane < 8) {    // D2: lambda_int folded into vic
    float la = -S.lamr[lane], th = S.lami[lane];
    float exps = expf(la * t);
    float sn, cs; sincosf(th * t, &sn, &cs);
    float denom = la * la + th * th;
    float sgn = (denom > 0.f) ? 1.f : ((denom < 0.f) ? -1.f : 0.f);
    float scale = sgn / fmaxf(denom, 1e-10f);
    float ci = scale * (exps * (la * cs + th * sn) - la);
    float si = scale * (exps * (la * sn - th * cs) + th);
    float e0 = S.vu[2 * lane], e1 = S.vu[2 * lane + 1];
    S.vic[2 * lane]     += ci * e0 - si * e1;
    S.vic[2 * lane + 1] += si * e0 + ci * e1;
  }
  WSYNC();  // S3
  if (lane < 16) {   // D3: out0 = Phi @ (init_cond + lambda_int)
    float fA[16], vv[16];
#pragma unroll
    for (int c = 0; c < 4; ++c) {
      float4 fv = *(const float4*)&S.F[lane * FS + 4 * c];
      fA[4*c+0]=fv.x; fA[4*c+1]=fv.y; fA[4*c+2]=fv.z; fA[4*c+3]=fv.w;
      float4 cv = *(const float4*)&S.vic[4 * c];
      vv[4*c+0]=cv.x; vv[4*c+1]=cv.y; vv[4*c+2]=cv.z; vv[4*c+3]=cv.w;
    }
    float d = 0.f;
#pragma unroll
    for (int k = 0; k < 16; ++k) d = fmaf(fA[k], vv[k], d);
    gOut0[(size_t)b * 16 + lane] = d;
  }
  WSYNC();  // S3b

  // ---- variance path ----
  mmv<false, FS, 16, FS>(S.W,  S.P, S.L1, i16, jg);        WSYNC();  // W = Pinv @ X0_var
  mmv<true,  FS, FS, 16>(S.L1, S.W, S.P,  i16, jg);        WSYNC();  // L1 = init_var
  mmv<false, FS, 16, FS>(S.W,  S.F, S.L1, i16, jg);        WSYNC();  // W = Phi @ init_var
  mmv<true,  FS, FS, 16>(S.L1, S.W, S.F,  i16, jg, true);  WSYNC();  // L1 = Hom_var (|diag|)
  mmv<false, FS, 16, FS>(S.W,  S.P, S.L4, i16, jg);        WSYNC();  // W = Pinv @ Q
  mmv<true,  FS, FS, 16>(S.L4, S.W, S.P,  i16, jg);        WSYNC();  // L4 = ext_s

  {  // sig_int -> W   (vcoef fetched from registers via cross-lane)
    const int j0 = jg << 2;
    const int p2 = i16 >> 1, aa = i16 & 1;
    const int sA = p2 * 8 + (j0 >> 1);   // source lane of first coef quad
    float4 c0, c1;
    c0.x = __shfl(vco.x, sA);     c0.y = __shfl(vco.y, sA);
    c0.z = __shfl(vco.z, sA);     c0.w = __shfl(vco.w, sA);
    c1.x = __shfl(vco.x, sA + 1); c1.y = __shfl(vco.y, sA + 1);
    c1.z = __shfl(vco.z, sA + 1); c1.w = __shfl(vco.w, sA + 1);
    float4 top = *(const float4*)&S.L4[(2 * p2) * 16 + j0];
    float4 bot = *(const float4*)&S.L4[(2 * p2 + 1) * 16 + j0];
    float tl[4] = { top.x, top.y, top.z, top.w };
    float bl[4] = { bot.x, bot.y, bot.z, bot.w };
    float r[4];
#pragma unroll
    for (int uu = 0; uu < 4; ++uu) {
      float4 c = (uu < 2) ? c0 : c1;
      const int off = 2 * (uu >> 1);
      float d11 = tl[off], d12 = tl[off + 1];
      float d21 = bl[off], d22 = bl[off + 1];
      float vcc = c.x, vsc = c.y, vcs = c.z, vss = c.w;
      const int bb = uu & 1;
      if (aa == 0)
        r[uu] = (bb == 0) ? (vcc * d11 - vsc * d21 - vcs * d12 + vss * d22)
                          : (vcs * d11 - vss * d21 + vcc * d12 - vsc * d22);
      else
        r[uu] = (bb == 0) ? (vsc * d11 + vcc * d21 - vss * d12 - vcs * d22)
                          : (vss * d11 + vcs * d21 + vsc * d12 + vcc * d22);
    }
    *(float4*)&S.W[i16 * FS + j0] = make_float4(r[0], r[1], r[2], r[3]);
  }
  WSYNC();
  mmv<false, FS, FS, 16>(S.L4, S.F, S.W, i16, jg);         WSYNC();  // L4 = Phi @ sig_int

  {  // out1 = Hom_var + L4 @ Phi^T
    const int j0 = jg << 2;
    float aA[16];
#pragma unroll
    for (int c = 0; c < 4; ++c) {
      float4 v = *(const float4*)&S.L4[i16 * 16 + 4 * c];
      aA[4*c+0]=v.x; aA[4*c+1]=v.y; aA[4*c+2]=v.z; aA[4*c+3]=v.w;
    }
    float acc[4];
#pragma unroll
    for (int c = 0; c < 4; ++c) {
      float bB[16];
#pragma unroll
      for (int cc = 0; cc < 4; ++cc) {
        float4 v = *(const float4*)&S.F[(j0 + c) * FS + 4 * cc];
        bB[4*cc+0]=v.x; bB[4*cc+1]=v.y; bB[4*cc+2]=v.z; bB[4*cc+3]=v.w;
      }
      float s = 0.f;
#pragma unroll
      for (int k = 0; k < 16; ++k) s = fmaf(aA[k], bB[k], s);
      acc[c] = s;
    }
    float4 hv = *(const float4*)&S.L1[i16 * 16 + j0];
    float4 o = make_float4(hv.x + acc[0], hv.y + acc[1], hv.z + acc[2], hv.w + acc[3]);
    *(float4*)&gOut1[(size_t)b * 256 + i16 * 16 + j0] = o;
  }
}

extern "C" void kernel_launch(void* const* d_in, const int* in_sizes, int n_in,
                              void* d_out, int out_size, void* d_ws, size_t ws_size,
                              hipStream_t stream) {
  const float* X0 = (const float*)d_in[0];
  const float* Xv = (const float*)d_in[1];
  const float* U  = (const float*)d_in[2];
  const float* T  = (const float*)d_in[3];
  const float* Q  = (const float*)d_in[4];
  const float* Lr = (const float*)d_in[5];
  const float* Li = (const float*)d_in[6];
  const float* Vr = (const float*)d_in[7];
  const float* Vi = (const float*)d_in[8];
  const int B = in_sizes[3];
  float* out0 = (float*)d_out;
  float* out1 = (float*)d_out + (size_t)B * 16;
  const int blocks = (B + 3) / 4;
  hipLaunchKernelGGL(nesde_kernel, dim3(blocks), dim3(256), 0, stream,
                     X0, Xv, U, T, Q, Lr, Li, Vr, Vi, out0, out1, B);
}